// Round 12
// baseline (248.726 us; speedup 1.0000x reference)
//
#include <hip/hip_runtime.h>
#include <hip/hip_fp16.h>

#define IN_DIM   128
#define HC       256   // HEADS*OUT_DIM
#define OUT_DIM  64
#define HEADS    4
#define NEG_SLOPE 0.2f
#define LN_EPS   1e-5f
#define DBITS    5
#define DPB      32    // dsts per bin
#define MAXBINS  4096  // supports N <= 131072
#define CAP      768   // LDS edge capacity per bin (mean ~512, sigma ~23)
#define NHIST    256   // histogram blocks in k_front
#define TILE_E   16384 // edges per scatter tile (two-pass, no reg arrays)

typedef short bf16x8 __attribute__((ext_vector_type(8)));
typedef float f32x4  __attribute__((ext_vector_type(4)));

__device__ __forceinline__ float lrelu(float a){ return a > 0.f ? a : NEG_SLOPE * a; }

__device__ __forceinline__ unsigned short f2bf(float f){
  unsigned u = __float_as_uint(f);
  u = u + 0x7fffu + ((u >> 16) & 1u);   // round-to-nearest-even
  return (unsigned short)(u >> 16);
}
__device__ __forceinline__ unsigned pk2(float a, float b){
  return (unsigned)f2bf(a) | ((unsigned)f2bf(b) << 16);
}
__device__ __forceinline__ __half2 u2h(unsigned u){ return *(__half2*)&u; }
__device__ __forceinline__ unsigned h2u(__half2 h){ return *(unsigned*)&h; }

// Per-wave int32/int64 layout detection: int64 node ids < 2^31 have zero odd
// 32-bit words; int32 layout would need 32 random node ids == 0 to fool this.
__device__ __forceinline__ bool detect32(const int* ei){
  int ln = threadIdx.x & 63;
  unsigned probe = (ln < 32) ? (unsigned)ei[2*ln + 1] : 0u;
  return __ballot(probe != 0) != 0ull;
}

// Fused front-end: blocks [0,128) transpose W -> Wt; blocks [128,128+NHIST)
// LDS-histogram bins, merged with one global atomic per (bin,block).
// bincnt pre-zeroed by hipMemsetAsync.
__global__ __launch_bounds__(256) void k_front(
    const float* __restrict__ W, unsigned short* __restrict__ Wt,
    const int* ei, int* __restrict__ bincnt, int E, int nbins)
{
  if (blockIdx.x < 128){
    int n = blockIdx.x*2 + (threadIdx.x >> 7);
    int k = threadIdx.x & 127;
    Wt[n*IN_DIM + k] = f2bf(W[k*HC + n]);
    return;
  }
  __shared__ int h[MAXBINS];
  bool i32 = detect32(ei);
  for (int i = threadIdx.x; i < nbins; i += 256) h[i] = 0;
  __syncthreads();
  int slot = blockIdx.x - 128;
  if (i32){
    const int* dstp = ei + E;
    for (int e = slot*256 + threadIdx.x; e < E; e += NHIST*256)
      atomicAdd(&h[dstp[e] >> DBITS], 1);
  } else {
    const long long* dstp = (const long long*)ei + E;
    for (int e = slot*256 + threadIdx.x; e < E; e += NHIST*256)
      atomicAdd(&h[((int)dstp[e]) >> DBITS], 1);
  }
  __syncthreads();
  for (int i = threadIdx.x; i < nbins; i += 256)
    if (h[i]) atomicAdd(&bincnt[i], h[i]);
}

// Single block, 1024 threads, 4 bins/thread: exclusive scan of bin counts.
__global__ __launch_bounds__(1024) void k_binscan(const int* __restrict__ bincnt,
    int* binstart, int* bincur, int nbins, int E)
{
  __shared__ int sh[1024];
  int t = threadIdx.x;
  int v[4]; int s = 0;
  #pragma unroll
  for (int k = 0; k < 4; ++k){
    int i = 4*t + k;
    v[k] = (i < nbins) ? bincnt[i] : 0;
    s += v[k];
  }
  sh[t] = s; __syncthreads();
  #pragma unroll
  for (int off = 1; off < 1024; off <<= 1){
    int u = (t >= off) ? sh[t-off] : 0;
    __syncthreads();
    sh[t] += u;
    __syncthreads();
  }
  int run = sh[t] - s;
  #pragma unroll
  for (int k = 0; k < 4; ++k){
    int i = 4*t + k;
    if (i < nbins){ binstart[i] = run; bincur[i] = run; }
    run += v[k];
  }
  if (t == 0) binstart[nbins] = E;
}

// ---- GEMM body (MFMA): xl_t = fp16(x@W) head-interleaved + logits ----
// BM=32 (2 sub-tiles) for 2x grid parallelism vs BM=64.
// LDS: sxa 8KB (x tile, XOR-swizzled) + sxl 8KB (per-sub output staging).
__device__ __forceinline__ void gemm_body(int bid, char* smem,
    const float* __restrict__ x, const unsigned short* __restrict__ Wt,
    const float* __restrict__ att_s, const float* __restrict__ att_d,
    __half* __restrict__ xl_t, float* __restrict__ a_src,
    float* __restrict__ a_dst, int N)
{
  unsigned short* sxl = (unsigned short*)(smem + 8192);  // 8KB per-sub staging
  int t = threadIdx.x;
  int nb = bid * 32;

  #pragma unroll
  for (int it = 0; it < 2; ++it){
    int idx = it*256 + t;
    int row = idx >> 4, seg = idx & 15;
    uint4 pk = make_uint4(0,0,0,0);
    if (nb + row < N){
      const float* xr = x + (size_t)(nb + row)*IN_DIM + seg*8;
      float4 f0 = *(const float4*)xr;
      float4 f1 = *(const float4*)(xr + 4);
      pk.x = pk2(f0.x, f0.y); pk.y = pk2(f0.z, f0.w);
      pk.z = pk2(f1.x, f1.y); pk.w = pk2(f1.z, f1.w);
    }
    int byte = (row*256 + seg*16) ^ ((row & 7) << 4);
    *(uint4*)(smem + byte) = pk;
  }
  __syncthreads();

  int w = t >> 6, l = t & 63;

  bf16x8 bfr[4][4];
  #pragma unroll
  for (int nt = 0; nt < 4; ++nt){
    int col = w*64 + nt*16 + (l & 15);
    #pragma unroll
    for (int ks = 0; ks < 4; ++ks)
      bfr[nt][ks] = *(const bf16x8*)(Wt + (size_t)col*IN_DIM + ks*32 + ((l >> 4) << 3));
  }
  float attS[4], attD[4];
  #pragma unroll
  for (int nt = 0; nt < 4; ++nt){
    attS[nt] = att_s[w*64 + nt*16 + (l & 15)];
    attD[nt] = att_d[w*64 + nt*16 + (l & 15)];
  }

  #pragma unroll
  for (int sub = 0; sub < 2; ++sub){
    bf16x8 afr[4];
    #pragma unroll
    for (int ks = 0; ks < 4; ++ks){
      int row = sub*16 + (l & 15);
      int byte = (row*256 + ks*64 + ((l >> 4) << 4)) ^ ((row & 7) << 4);
      afr[ks] = *(const bf16x8*)(smem + byte);
    }
    f32x4 acc[4] = {{0,0,0,0},{0,0,0,0},{0,0,0,0},{0,0,0,0}};
    #pragma unroll
    for (int nt = 0; nt < 4; ++nt)
      #pragma unroll
      for (int ks = 0; ks < 4; ++ks)
        acc[nt] = __builtin_amdgcn_mfma_f32_16x16x32_bf16(afr[ks], bfr[nt][ks], acc[nt], 0, 0, 0);

    #pragma unroll
    for (int r = 0; r < 4; ++r){
      float ps = 0.f, pd = 0.f;
      #pragma unroll
      for (int nt = 0; nt < 4; ++nt){
        ps = fmaf(acc[nt][r], attS[nt], ps);
        pd = fmaf(acc[nt][r], attD[nt], pd);
      }
      #pragma unroll
      for (int o = 8; o; o >>= 1){ ps += __shfl_xor(ps, o); pd += __shfl_xor(pd, o); }
      int node = nb + sub*16 + (l >> 4)*4 + r;
      if ((l & 15) == 0 && node < N){
        a_src[node*4 + w] = ps;
        a_dst[node*4 + w] = pd;
      }
    }

    #pragma unroll
    for (int nt = 0; nt < 4; ++nt){
      int ch = nt*16 + (l & 15);
      #pragma unroll
      for (int r = 0; r < 4; ++r){
        int row = (l >> 4)*4 + r;
        sxl[row*HC + ch*4 + w] = __half_as_ushort(__float2half(acc[nt][r]));
      }
    }
    __syncthreads();
    const uint4* s4 = (const uint4*)sxl;
    uint4* g4 = (uint4*)(xl_t + (size_t)(nb + sub*16)*HC);
    #pragma unroll
    for (int c = t; c < 512; c += 256){
      int row = c >> 5;
      if (nb + sub*16 + row < N) g4[c] = s4[c];
    }
    __syncthreads();
  }
}

// ---- binscatter body: two-pass partition of a 16K-edge tile ----
// Pass A: count dsts per bin (LDS packed 2x16-bit). Reserve one global range
// per (bin,tile). Pass B: re-read edges, rank via re-zeroed LDS counters,
// write tmp = src | (dst & 31) << 20  (requires N < 2^20).
__device__ __forceinline__ void scat_body(int bid, char* smem,
    const int* ei, int* bincur, unsigned* tmp, int E, int nbins)
{
  int* h32  = (int*)smem;                  // 8KB packed counters
  int* base = (int*)(smem + 8192);         // 16KB global bases
  bool i32 = detect32(ei);
  int e0 = bid * TILE_E;
  int e1 = e0 + TILE_E; if (e1 > E) e1 = E;
  int nh = (nbins + 1) >> 1;
  for (int i = threadIdx.x; i < nh; i += 256) h32[i] = 0;
  __syncthreads();
  // pass A: count
  if (i32){
    const int* dstp = ei + E;
    for (int e = e0 + threadIdx.x; e < e1; e += 256){
      int b = dstp[e] >> DBITS;
      atomicAdd(&h32[b >> 1], 1 << ((b & 1) << 4));
    }
  } else {
    const long long* dstp = (const long long*)ei + E;
    for (int e = e0 + threadIdx.x; e < e1; e += 256){
      int b = ((int)dstp[e]) >> DBITS;
      atomicAdd(&h32[b >> 1], 1 << ((b & 1) << 4));
    }
  }
  __syncthreads();
  // reserve global ranges (one atomic per nonzero (bin,tile))
  for (int i = threadIdx.x; i < nbins; i += 256){
    int c = (h32[i >> 1] >> ((i & 1) << 4)) & 0xFFFF;
    base[i] = c ? atomicAdd(&bincur[i], c) : 0;
  }
  __syncthreads();
  for (int i = threadIdx.x; i < nh; i += 256) h32[i] = 0;
  __syncthreads();
  // pass B: rank + write
  for (int e = e0 + threadIdx.x; e < e1; e += 256){
    int s, d;
    if (i32){ s = ei[e]; d = ei[E + e]; }
    else {
      s = (int)((const long long*)ei)[e];
      d = (int)((const long long*)ei)[(size_t)E + e];
    }
    int b = d >> DBITS;
    int sh = (b & 1) << 4;
    unsigned old = (unsigned)atomicAdd(&h32[b >> 1], 1 << sh);
    int r = (int)((old >> sh) & 0xFFFFu);
    tmp[base[b] + r] = (unsigned)s | ((unsigned)(d & (DPB-1)) << 20);
  }
}

// Fused dispatch: gemm blocks [0, gemmBlocks), binscatter blocks after.
__global__ __launch_bounds__(256) void k_gemm_scat(
    const float* __restrict__ x, const unsigned short* __restrict__ Wt,
    const float* __restrict__ att_s, const float* __restrict__ att_d,
    __half* __restrict__ xl_t, float* __restrict__ a_src, float* __restrict__ a_dst,
    int N, const int* ei, int* bincur, unsigned* tmp, int E, int nbins,
    int gemmBlocks)
{
  __shared__ char smem[24576];
  int bid = (int)blockIdx.x;
  if (bid < gemmBlocks)
    gemm_body(bid, smem, x, Wt, att_s, att_d, xl_t, a_src, a_dst, N);
  else
    scat_body(bid - gemmBlocks, smem, ei, bincur, tmp, E, nbins);
}

// One block per bin (32 dsts): in-LDS binsort (count -> scan -> rank-scatter),
// then 16-lane groups process 2 dsts each with direct-softmax attention
// (logits O(1); shift-invariance) + head-avg + LN. PV: group gathers one
// 512B fp16 row per edge (lane i covers 32B = 4ch x 4heads), unroll 4.
__global__ __launch_bounds__(256) void k_node(
    const int* __restrict__ binstart, const unsigned* __restrict__ tmp,
    int* __restrict__ csr,
    const float4* __restrict__ a_src4, const float4* __restrict__ a_dst4,
    const __half* __restrict__ xl_t,
    const float* __restrict__ bias, const float* __restrict__ gamma,
    const float* __restrict__ beta, float* __restrict__ out, int N)
{
  __shared__ int cnt[DPB], sc[DPB], cur[DPB];
  __shared__ int lcsr[CAP];
  __shared__ uint2 wlds[16][16];
  int b = blockIdx.x, tid = threadIdx.x;
  int s0 = binstart[b], s1 = binstart[b+1];
  int seg = s1 - s0;

  if (tid < DPB){ cnt[tid] = 0; }
  __syncthreads();
  for (int e = s0 + tid; e < s1; e += 256)
    atomicAdd(&cnt[(tmp[e] >> 20) & (DPB-1)], 1);
  __syncthreads();
  if (tid < DPB) sc[tid] = cnt[tid];
  __syncthreads();
  #pragma unroll
  for (int off = 1; off < DPB; off <<= 1){
    int v = (tid < DPB && tid >= off) ? sc[tid-off] : 0;
    __syncthreads();
    if (tid < DPB) sc[tid] += v;
    __syncthreads();
  }
  if (tid < DPB){ int ex = sc[tid] - cnt[tid]; sc[tid] = ex; cur[tid] = ex; }
  __syncthreads();

  // rank-scatter into LDS (global csr fallback for pathological bins)
  int* ebuf = (seg <= CAP) ? lcsr : (csr + s0);
  for (int e = s0 + tid; e < s1; e += 256){
    unsigned u = tmp[e];
    int dl = (u >> 20) & (DPB-1);
    int r = atomicAdd(&cur[dl], 1);
    ebuf[r] = (int)(u & 0xFFFFFu);
  }
  __syncthreads();

  int gg = tid >> 4, i = tid & 15;
  #pragma unroll
  for (int n = 0; n < 2; ++n){
    int dl = gg*2 + n;
    int node = b*DPB + dl;
    if (node >= N) continue;
    int lstart = sc[dl], lend = lstart + cnt[dl];

    float4 ad  = a_dst4[node];
    float4 asl = a_src4[node];
    float es0 = __expf(lrelu(asl.x + ad.x));
    float es1 = __expf(lrelu(asl.y + ad.y));
    float es2 = __expf(lrelu(asl.z + ad.z));
    float es3 = __expf(lrelu(asl.w + ad.w));

    __half2 s01 = __floats2half2_rn(es0, es1);
    __half2 s23 = __floats2half2_rn(es2, es3);
    const uint4* ps = (const uint4*)((const char*)xl_t + ((size_t)node*512 + (i << 5)));
    uint4 xa = ps[0], xb = ps[1];
    __half2 acc[8];
    acc[0] = __hmul2(s01, u2h(xa.x));
    acc[1] = __hmul2(s23, u2h(xa.y));
    acc[2] = __hmul2(s01, u2h(xa.z));
    acc[3] = __hmul2(s23, u2h(xa.w));
    acc[4] = __hmul2(s01, u2h(xb.x));
    acc[5] = __hmul2(s23, u2h(xb.y));
    acc[6] = __hmul2(s01, u2h(xb.z));
    acc[7] = __hmul2(s23, u2h(xb.w));
    float lp0 = 0.f, lp1 = 0.f, lp2 = 0.f, lp3 = 0.f;

    for (int t2 = lstart; t2 < lend; t2 += 16){
      int rem = lend - t2; if (rem > 16) rem = 16;
      float e0 = 0.f, e1 = 0.f, e2 = 0.f, e3 = 0.f;
      if (i < rem){
        int sid = ebuf[t2 + i];
        float4 as4 = a_src4[sid];
        e0 = __expf(lrelu(as4.x + ad.x));
        e1 = __expf(lrelu(as4.y + ad.y));
        e2 = __expf(lrelu(as4.z + ad.z));
        e3 = __expf(lrelu(as4.w + ad.w));
        lp0 += e0; lp1 += e1; lp2 += e2; lp3 += e3;
      }
      wlds[gg][i] = make_uint2(h2u(__floats2half2_rn(e0, e1)),
                               h2u(__floats2half2_rn(e2, e3)));

      #pragma unroll 4
      for (int j = 0; j < rem; ++j){
        uint2 wpk = wlds[gg][j];
        int sj = ebuf[t2 + j];
        __half2 w01 = u2h(wpk.x), w23 = u2h(wpk.y);
        const uint4* p = (const uint4*)((const char*)xl_t + ((size_t)sj*512 + (i << 5)));
        uint4 ya = p[0], yb = p[1];
        acc[0] = __hfma2(w01, u2h(ya.x), acc[0]);
        acc[1] = __hfma2(w23, u2h(ya.y), acc[1]);
        acc[2] = __hfma2(w01, u2h(ya.z), acc[2]);
        acc[3] = __hfma2(w23, u2h(ya.w), acc[3]);
        acc[4] = __hfma2(w01, u2h(yb.x), acc[4]);
        acc[5] = __hfma2(w23, u2h(yb.y), acc[5]);
        acc[6] = __hfma2(w01, u2h(yb.z), acc[6]);
        acc[7] = __hfma2(w23, u2h(yb.w), acc[7]);
      }
    }

    __half2 lp01 = __floats2half2_rn(lp0, lp1);
    __half2 lp23 = __floats2half2_rn(lp2, lp3);
    #pragma unroll
    for (int o = 8; o; o >>= 1){
      lp01 = __hadd2(lp01, u2h(__shfl_xor(h2u(lp01), o)));
      lp23 = __hadd2(lp23, u2h(__shfl_xor(h2u(lp23), o)));
    }
    float r0 = __builtin_amdgcn_rcpf(__low2float(lp01) + es0);
    float r1 = __builtin_amdgcn_rcpf(__high2float(lp01) + es1);
    float r2 = __builtin_amdgcn_rcpf(__low2float(lp23) + es2);
    float r3 = __builtin_amdgcn_rcpf(__high2float(lp23) + es3);

    float4 b4 = *(const float4*)(bias + 4*i);
    float o0 = 0.25f*(__low2float(acc[0])*r0 + __high2float(acc[0])*r1 +
                      __low2float(acc[1])*r2 + __high2float(acc[1])*r3) + b4.x;
    float o1 = 0.25f*(__low2float(acc[2])*r0 + __high2float(acc[2])*r1 +
                      __low2float(acc[3])*r2 + __high2float(acc[3])*r3) + b4.y;
    float o2 = 0.25f*(__low2float(acc[4])*r0 + __high2float(acc[4])*r1 +
                      __low2float(acc[5])*r2 + __high2float(acc[5])*r3) + b4.z;
    float o3 = 0.25f*(__low2float(acc[6])*r0 + __high2float(acc[6])*r1 +
                      __low2float(acc[7])*r2 + __high2float(acc[7])*r3) + b4.w;

    float s  = o0 + o1 + o2 + o3;
    float sq = o0*o0 + o1*o1 + o2*o2 + o3*o3;
    #pragma unroll
    for (int o = 8; o; o >>= 1){
      s  += __shfl_xor(s, o);
      sq += __shfl_xor(sq, o);
    }
    float mu = s * (1.f/OUT_DIM);
    float var = sq * (1.f/OUT_DIM) - mu*mu;
    float rs = rsqrtf(var + LN_EPS);
    float4 g4v = *(const float4*)(gamma + 4*i);
    float4 be4 = *(const float4*)(beta + 4*i);
    float4 ov;
    ov.x = (o0 - mu)*rs*g4v.x + be4.x;
    ov.y = (o1 - mu)*rs*g4v.y + be4.y;
    ov.z = (o2 - mu)*rs*g4v.z + be4.z;
    ov.w = (o3 - mu)*rs*g4v.w + be4.w;
    *(float4*)(out + (size_t)node*OUT_DIM + 4*i) = ov;
  }
}

extern "C" void kernel_launch(void* const* d_in, const int* in_sizes, int n_in,
                              void* d_out, int out_size, void* d_ws, size_t ws_size,
                              hipStream_t stream)
{
  const float* x     = (const float*)d_in[0];
  const int*   ei    = (const int*)d_in[1];
  const float* W     = (const float*)d_in[2];
  const float* att_s = (const float*)d_in[3];
  const float* att_d = (const float*)d_in[4];
  const float* bias  = (const float*)d_in[5];
  const float* gamma = (const float*)d_in[6];
  const float* beta  = (const float*)d_in[7];
  float* out = (float*)d_out;

  int N = in_sizes[0] / IN_DIM;
  int E = in_sizes[1] / 2;
  int nbins = (N + DPB - 1) >> DBITS;

  char* ws = (char*)d_ws;
  __half* xl_t = (__half*)ws;                   ws += (size_t)N*HC*sizeof(__half);
  float* a_src = (float*)ws;                    ws += (size_t)N*HEADS*sizeof(float);
  float* a_dst = (float*)ws;                    ws += (size_t)N*HEADS*sizeof(float);
  int* csr      = (int*)ws;                     ws += (size_t)E*sizeof(int);
  unsigned* tmp = (unsigned*)ws;                ws += (size_t)E*sizeof(unsigned);
  int* bincnt   = (int*)ws;                     ws += MAXBINS*sizeof(int);
  int* binstart = (int*)ws;                     ws += (MAXBINS+1)*sizeof(int);
  int* bincur   = (int*)ws;                     ws += MAXBINS*sizeof(int);
  unsigned short* Wt = (unsigned short*)ws;     ws += (size_t)HC*IN_DIM*sizeof(unsigned short);

  int gemmBlocks = (N + 31)/32;
  int scatBlocks = (E + TILE_E - 1)/TILE_E;

  hipMemsetAsync(bincnt, 0, (size_t)nbins*sizeof(int), stream);
  k_front   <<<128 + NHIST, 256, 0, stream>>>(W, Wt, ei, bincnt, E, nbins);
  k_binscan <<<1, 1024, 0, stream>>>(bincnt, binstart, bincur, nbins, E);
  k_gemm_scat<<<gemmBlocks + scatBlocks, 256, 0, stream>>>(
      x, Wt, att_s, att_d, xl_t, a_src, a_dst, N, ei, bincur, tmp, E, nbins,
      gemmBlocks);
  k_node    <<<nbins, 256, 0, stream>>>(binstart, tmp, csr,
              (const float4*)a_src, (const float4*)a_dst, xl_t,
              bias, gamma, beta, out, N);
}

// Round 13
// 219.698 us; speedup vs baseline: 1.1321x; 1.1321x over previous
//
#include <hip/hip_runtime.h>
#include <hip/hip_fp16.h>

#define IN_DIM   128
#define HC       256   // HEADS*OUT_DIM
#define OUT_DIM  64
#define HEADS    4
#define NEG_SLOPE 0.2f
#define LN_EPS   1e-5f
#define DBITS    5
#define DPB      32    // dsts per bin
#define MAXBINS  4096  // supports N <= 131072
#define CAP      768   // LDS edge capacity per bin (mean ~512, sigma ~23)
#define NHIST    256   // histogram blocks in k_front
#define SCAT_TPE 16    // edges per thread in binscatter (tile = 4096)

typedef short bf16x8 __attribute__((ext_vector_type(8)));
typedef float f32x4  __attribute__((ext_vector_type(4)));

__device__ __forceinline__ float lrelu(float a){ return a > 0.f ? a : NEG_SLOPE * a; }

__device__ __forceinline__ unsigned short f2bf(float f){
  unsigned u = __float_as_uint(f);
  u = u + 0x7fffu + ((u >> 16) & 1u);   // round-to-nearest-even
  return (unsigned short)(u >> 16);
}
__device__ __forceinline__ unsigned pk2(float a, float b){
  return (unsigned)f2bf(a) | ((unsigned)f2bf(b) << 16);
}
__device__ __forceinline__ __half2 u2h(unsigned u){ return *(__half2*)&u; }
__device__ __forceinline__ unsigned h2u(__half2 h){ return *(unsigned*)&h; }

// Per-wave int32/int64 layout detection: int64 node ids < 2^31 have zero odd
// 32-bit words; int32 layout would need 32 random node ids == 0 to fool this.
__device__ __forceinline__ bool detect32(const int* ei){
  int ln = threadIdx.x & 63;
  unsigned probe = (ln < 32) ? (unsigned)ei[2*ln + 1] : 0u;
  return __ballot(probe != 0) != 0ull;
}

// Fused front-end: blocks [0,128) transpose W -> Wt; blocks [128,128+NHIST)
// LDS-histogram bins, merged with one global atomic per (bin,block).
// bincnt pre-zeroed by hipMemsetAsync.
__global__ __launch_bounds__(256) void k_front(
    const float* __restrict__ W, unsigned short* __restrict__ Wt,
    const int* ei, int* __restrict__ bincnt, int E, int nbins)
{
  if (blockIdx.x < 128){
    int n = blockIdx.x*2 + (threadIdx.x >> 7);
    int k = threadIdx.x & 127;
    Wt[n*IN_DIM + k] = f2bf(W[k*HC + n]);
    return;
  }
  __shared__ int h[MAXBINS];
  bool i32 = detect32(ei);
  for (int i = threadIdx.x; i < nbins; i += 256) h[i] = 0;
  __syncthreads();
  int slot = blockIdx.x - 128;
  if (i32){
    const int* dstp = ei + E;
    for (int e = slot*256 + threadIdx.x; e < E; e += NHIST*256)
      atomicAdd(&h[dstp[e] >> DBITS], 1);
  } else {
    const long long* dstp = (const long long*)ei + E;
    for (int e = slot*256 + threadIdx.x; e < E; e += NHIST*256)
      atomicAdd(&h[((int)dstp[e]) >> DBITS], 1);
  }
  __syncthreads();
  for (int i = threadIdx.x; i < nbins; i += 256)
    if (h[i]) atomicAdd(&bincnt[i], h[i]);
}

// Single block, 1024 threads, 4 bins/thread: exclusive scan of bin counts.
__global__ __launch_bounds__(1024) void k_binscan(const int* __restrict__ bincnt,
    int* binstart, int* bincur, int nbins, int E)
{
  __shared__ int sh[1024];
  int t = threadIdx.x;
  int v[4]; int s = 0;
  #pragma unroll
  for (int k = 0; k < 4; ++k){
    int i = 4*t + k;
    v[k] = (i < nbins) ? bincnt[i] : 0;
    s += v[k];
  }
  sh[t] = s; __syncthreads();
  #pragma unroll
  for (int off = 1; off < 1024; off <<= 1){
    int u = (t >= off) ? sh[t-off] : 0;
    __syncthreads();
    sh[t] += u;
    __syncthreads();
  }
  int run = sh[t] - s;
  #pragma unroll
  for (int k = 0; k < 4; ++k){
    int i = 4*t + k;
    if (i < nbins){ binstart[i] = run; bincur[i] = run; }
    run += v[k];
  }
  if (t == 0) binstart[nbins] = E;
}

// ---- GEMM body (MFMA): xl_t = fp16(x@W) head-interleaved + logits ----
// LDS: sxa 16KB (x tile, XOR-swizzled) + sxl 8KB (per-sub output staging).
__device__ __forceinline__ void gemm_body(int bid, char* smem,
    const float* __restrict__ x, const unsigned short* __restrict__ Wt,
    const float* __restrict__ att_s, const float* __restrict__ att_d,
    __half* __restrict__ xl_t, float* __restrict__ a_src,
    float* __restrict__ a_dst, int N)
{
  unsigned short* sxl = (unsigned short*)(smem + 16384);  // 8KB per-sub staging
  int t = threadIdx.x;
  int nb = bid * 64;

  #pragma unroll
  for (int it = 0; it < 4; ++it){
    int idx = it*256 + t;
    int row = idx >> 4, seg = idx & 15;
    uint4 pk = make_uint4(0,0,0,0);
    if (nb + row < N){
      const float* xr = x + (size_t)(nb + row)*IN_DIM + seg*8;
      float4 f0 = *(const float4*)xr;
      float4 f1 = *(const float4*)(xr + 4);
      pk.x = pk2(f0.x, f0.y); pk.y = pk2(f0.z, f0.w);
      pk.z = pk2(f1.x, f1.y); pk.w = pk2(f1.z, f1.w);
    }
    int byte = (row*256 + seg*16) ^ ((row & 7) << 4);
    *(uint4*)(smem + byte) = pk;
  }
  __syncthreads();

  int w = t >> 6, l = t & 63;

  bf16x8 bfr[4][4];
  #pragma unroll
  for (int nt = 0; nt < 4; ++nt){
    int col = w*64 + nt*16 + (l & 15);
    #pragma unroll
    for (int ks = 0; ks < 4; ++ks)
      bfr[nt][ks] = *(const bf16x8*)(Wt + (size_t)col*IN_DIM + ks*32 + ((l >> 4) << 3));
  }
  float attS[4], attD[4];
  #pragma unroll
  for (int nt = 0; nt < 4; ++nt){
    attS[nt] = att_s[w*64 + nt*16 + (l & 15)];
    attD[nt] = att_d[w*64 + nt*16 + (l & 15)];
  }

  #pragma unroll
  for (int sub = 0; sub < 4; ++sub){
    bf16x8 afr[4];
    #pragma unroll
    for (int ks = 0; ks < 4; ++ks){
      int row = sub*16 + (l & 15);
      int byte = (row*256 + ks*64 + ((l >> 4) << 4)) ^ ((row & 7) << 4);
      afr[ks] = *(const bf16x8*)(smem + byte);
    }
    f32x4 acc[4] = {{0,0,0,0},{0,0,0,0},{0,0,0,0},{0,0,0,0}};
    #pragma unroll
    for (int nt = 0; nt < 4; ++nt)
      #pragma unroll
      for (int ks = 0; ks < 4; ++ks)
        acc[nt] = __builtin_amdgcn_mfma_f32_16x16x32_bf16(afr[ks], bfr[nt][ks], acc[nt], 0, 0, 0);

    #pragma unroll
    for (int r = 0; r < 4; ++r){
      float ps = 0.f, pd = 0.f;
      #pragma unroll
      for (int nt = 0; nt < 4; ++nt){
        ps = fmaf(acc[nt][r], attS[nt], ps);
        pd = fmaf(acc[nt][r], attD[nt], pd);
      }
      #pragma unroll
      for (int o = 8; o; o >>= 1){ ps += __shfl_xor(ps, o); pd += __shfl_xor(pd, o); }
      int node = nb + sub*16 + (l >> 4)*4 + r;
      if ((l & 15) == 0 && node < N){
        a_src[node*4 + w] = ps;
        a_dst[node*4 + w] = pd;
      }
    }

    #pragma unroll
    for (int nt = 0; nt < 4; ++nt){
      int ch = nt*16 + (l & 15);
      #pragma unroll
      for (int r = 0; r < 4; ++r){
        int row = (l >> 4)*4 + r;
        sxl[row*HC + ch*4 + w] = __half_as_ushort(__float2half(acc[nt][r]));
      }
    }
    __syncthreads();
    const uint4* s4 = (const uint4*)sxl;
    uint4* g4 = (uint4*)(xl_t + (size_t)(nb + sub*16)*HC);
    #pragma unroll
    for (int c = t; c < 512; c += 256){
      int row = c >> 5;
      if (nb + sub*16 + row < N) g4[c] = s4[c];
    }
    __syncthreads();
  }
}

// ---- binscatter body: partition edges into bin segments ----
// LDS counters packed 2x16-bit per int (counts <= 4096, no carry).
// tmp word = src | (dst & 31) << 20  (requires N < 2^20).
__device__ __forceinline__ void scat_body(int bid, char* smem,
    const int* ei, int* bincur, unsigned* tmp, int E, int nbins)
{
  int* h32  = (int*)smem;                  // 8KB packed counters
  int* base = (int*)(smem + 8192);         // 16KB
  bool i32 = detect32(ei);
  int tile0 = bid * (256*SCAT_TPE);
  for (int i = threadIdx.x; i < ((nbins+1)>>1); i += 256) h32[i] = 0;
  __syncthreads();
  unsigned pk[SCAT_TPE]; int rk[SCAT_TPE];
  #pragma unroll
  for (int k = 0; k < SCAT_TPE; ++k){
    int e = tile0 + k*256 + threadIdx.x;
    if (e < E){
      int s, d;
      if (i32){ s = ei[e]; d = ei[E + e]; }
      else {
        s = (int)((const long long*)ei)[e];
        d = (int)((const long long*)ei)[(size_t)E + e];
      }
      int b = d >> DBITS;
      pk[k] = (unsigned)s | ((unsigned)(d & (DPB-1)) << 20);
      int sh = (b & 1) << 4;
      unsigned old = (unsigned)atomicAdd(&h32[b >> 1], 1 << sh);
      rk[k] = (int)((old >> sh) & 0xFFFFu) | (b << 12);
    }
  }
  __syncthreads();
  for (int i = threadIdx.x; i < nbins; i += 256){
    int c = (h32[i >> 1] >> ((i & 1) << 4)) & 0xFFFF;
    base[i] = c ? atomicAdd(&bincur[i], c) : 0;
  }
  __syncthreads();
  #pragma unroll
  for (int k = 0; k < SCAT_TPE; ++k){
    int e = tile0 + k*256 + threadIdx.x;
    if (e < E){
      int b = rk[k] >> 12, r = rk[k] & 0xFFF;
      tmp[base[b] + r] = pk[k];
    }
  }
}

// Fused dispatch: gemm blocks [0, gemmBlocks), binscatter blocks after.
__global__ __launch_bounds__(256) void k_gemm_scat(
    const float* __restrict__ x, const unsigned short* __restrict__ Wt,
    const float* __restrict__ att_s, const float* __restrict__ att_d,
    __half* __restrict__ xl_t, float* __restrict__ a_src, float* __restrict__ a_dst,
    int N, const int* ei, int* bincur, unsigned* tmp, int E, int nbins,
    int gemmBlocks)
{
  __shared__ char smem[24576];
  int bid = (int)blockIdx.x;
  if (bid < gemmBlocks)
    gemm_body(bid, smem, x, Wt, att_s, att_d, xl_t, a_src, a_dst, N);
  else
    scat_body(bid - gemmBlocks, smem, ei, bincur, tmp, E, nbins);
}

// One block per bin (32 dsts): in-LDS binsort (count -> scan -> rank-scatter),
// then 16-lane groups process 2 dsts each with direct-softmax attention
// (logits O(1); shift-invariance) + head-avg + LN. PV: group gathers one
// 512B fp16 row per edge (lane i covers 32B = 4ch x 4heads), unroll 4.
__global__ __launch_bounds__(256) void k_node(
    const int* __restrict__ binstart, const unsigned* __restrict__ tmp,
    int* __restrict__ csr,
    const float4* __restrict__ a_src4, const float4* __restrict__ a_dst4,
    const __half* __restrict__ xl_t,
    const float* __restrict__ bias, const float* __restrict__ gamma,
    const float* __restrict__ beta, float* __restrict__ out, int N)
{
  __shared__ int cnt[DPB], sc[DPB], cur[DPB];
  __shared__ int lcsr[CAP];
  __shared__ uint2 wlds[16][16];
  int b = blockIdx.x, tid = threadIdx.x;
  int s0 = binstart[b], s1 = binstart[b+1];
  int seg = s1 - s0;

  if (tid < DPB){ cnt[tid] = 0; }
  __syncthreads();
  for (int e = s0 + tid; e < s1; e += 256)
    atomicAdd(&cnt[(tmp[e] >> 20) & (DPB-1)], 1);
  __syncthreads();
  if (tid < DPB) sc[tid] = cnt[tid];
  __syncthreads();
  #pragma unroll
  for (int off = 1; off < DPB; off <<= 1){
    int v = (tid < DPB && tid >= off) ? sc[tid-off] : 0;
    __syncthreads();
    if (tid < DPB) sc[tid] += v;
    __syncthreads();
  }
  if (tid < DPB){ int ex = sc[tid] - cnt[tid]; sc[tid] = ex; cur[tid] = ex; }
  __syncthreads();

  // rank-scatter into LDS (global csr fallback for pathological bins)
  int* ebuf = (seg <= CAP) ? lcsr : (csr + s0);
  for (int e = s0 + tid; e < s1; e += 256){
    unsigned u = tmp[e];
    int dl = (u >> 20) & (DPB-1);
    int r = atomicAdd(&cur[dl], 1);
    ebuf[r] = (int)(u & 0xFFFFFu);
  }
  __syncthreads();

  int gg = tid >> 4, i = tid & 15;
  #pragma unroll
  for (int n = 0; n < 2; ++n){
    int dl = gg*2 + n;
    int node = b*DPB + dl;
    if (node >= N) continue;
    int lstart = sc[dl], lend = lstart + cnt[dl];

    float4 ad  = a_dst4[node];
    float4 asl = a_src4[node];
    float es0 = __expf(lrelu(asl.x + ad.x));
    float es1 = __expf(lrelu(asl.y + ad.y));
    float es2 = __expf(lrelu(asl.z + ad.z));
    float es3 = __expf(lrelu(asl.w + ad.w));

    __half2 s01 = __floats2half2_rn(es0, es1);
    __half2 s23 = __floats2half2_rn(es2, es3);
    const uint4* ps = (const uint4*)((const char*)xl_t + ((size_t)node*512 + (i << 5)));
    uint4 xa = ps[0], xb = ps[1];
    __half2 acc[8];
    acc[0] = __hmul2(s01, u2h(xa.x));
    acc[1] = __hmul2(s23, u2h(xa.y));
    acc[2] = __hmul2(s01, u2h(xa.z));
    acc[3] = __hmul2(s23, u2h(xa.w));
    acc[4] = __hmul2(s01, u2h(xb.x));
    acc[5] = __hmul2(s23, u2h(xb.y));
    acc[6] = __hmul2(s01, u2h(xb.z));
    acc[7] = __hmul2(s23, u2h(xb.w));
    float lp0 = 0.f, lp1 = 0.f, lp2 = 0.f, lp3 = 0.f;

    for (int t2 = lstart; t2 < lend; t2 += 16){
      int rem = lend - t2; if (rem > 16) rem = 16;
      float e0 = 0.f, e1 = 0.f, e2 = 0.f, e3 = 0.f;
      if (i < rem){
        int sid = ebuf[t2 + i];
        float4 as4 = a_src4[sid];
        e0 = __expf(lrelu(as4.x + ad.x));
        e1 = __expf(lrelu(as4.y + ad.y));
        e2 = __expf(lrelu(as4.z + ad.z));
        e3 = __expf(lrelu(as4.w + ad.w));
        lp0 += e0; lp1 += e1; lp2 += e2; lp3 += e3;
      }
      wlds[gg][i] = make_uint2(h2u(__floats2half2_rn(e0, e1)),
                               h2u(__floats2half2_rn(e2, e3)));

      #pragma unroll 4
      for (int j = 0; j < rem; ++j){
        uint2 wpk = wlds[gg][j];
        int sj = ebuf[t2 + j];
        __half2 w01 = u2h(wpk.x), w23 = u2h(wpk.y);
        const uint4* p = (const uint4*)((const char*)xl_t + ((size_t)sj*512 + (i << 5)));
        uint4 ya = p[0], yb = p[1];
        acc[0] = __hfma2(w01, u2h(ya.x), acc[0]);
        acc[1] = __hfma2(w23, u2h(ya.y), acc[1]);
        acc[2] = __hfma2(w01, u2h(ya.z), acc[2]);
        acc[3] = __hfma2(w23, u2h(ya.w), acc[3]);
        acc[4] = __hfma2(w01, u2h(yb.x), acc[4]);
        acc[5] = __hfma2(w23, u2h(yb.y), acc[5]);
        acc[6] = __hfma2(w01, u2h(yb.z), acc[6]);
        acc[7] = __hfma2(w23, u2h(yb.w), acc[7]);
      }
    }

    __half2 lp01 = __floats2half2_rn(lp0, lp1);
    __half2 lp23 = __floats2half2_rn(lp2, lp3);
    #pragma unroll
    for (int o = 8; o; o >>= 1){
      lp01 = __hadd2(lp01, u2h(__shfl_xor(h2u(lp01), o)));
      lp23 = __hadd2(lp23, u2h(__shfl_xor(h2u(lp23), o)));
    }
    float r0 = __builtin_amdgcn_rcpf(__low2float(lp01) + es0);
    float r1 = __builtin_amdgcn_rcpf(__high2float(lp01) + es1);
    float r2 = __builtin_amdgcn_rcpf(__low2float(lp23) + es2);
    float r3 = __builtin_amdgcn_rcpf(__high2float(lp23) + es3);

    float4 b4 = *(const float4*)(bias + 4*i);
    float o0 = 0.25f*(__low2float(acc[0])*r0 + __high2float(acc[0])*r1 +
                      __low2float(acc[1])*r2 + __high2float(acc[1])*r3) + b4.x;
    float o1 = 0.25f*(__low2float(acc[2])*r0 + __high2float(acc[2])*r1 +
                      __low2float(acc[3])*r2 + __high2float(acc[3])*r3) + b4.y;
    float o2 = 0.25f*(__low2float(acc[4])*r0 + __high2float(acc[4])*r1 +
                      __low2float(acc[5])*r2 + __high2float(acc[5])*r3) + b4.z;
    float o3 = 0.25f*(__low2float(acc[6])*r0 + __high2float(acc[6])*r1 +
                      __low2float(acc[7])*r2 + __high2float(acc[7])*r3) + b4.w;

    float s  = o0 + o1 + o2 + o3;
    float sq = o0*o0 + o1*o1 + o2*o2 + o3*o3;
    #pragma unroll
    for (int o = 8; o; o >>= 1){
      s  += __shfl_xor(s, o);
      sq += __shfl_xor(sq, o);
    }
    float mu = s * (1.f/OUT_DIM);
    float var = sq * (1.f/OUT_DIM) - mu*mu;
    float rs = rsqrtf(var + LN_EPS);
    float4 g4v = *(const float4*)(gamma + 4*i);
    float4 be4 = *(const float4*)(beta + 4*i);
    float4 ov;
    ov.x = (o0 - mu)*rs*g4v.x + be4.x;
    ov.y = (o1 - mu)*rs*g4v.y + be4.y;
    ov.z = (o2 - mu)*rs*g4v.z + be4.z;
    ov.w = (o3 - mu)*rs*g4v.w + be4.w;
    *(float4*)(out + (size_t)node*OUT_DIM + 4*i) = ov;
  }
}

extern "C" void kernel_launch(void* const* d_in, const int* in_sizes, int n_in,
                              void* d_out, int out_size, void* d_ws, size_t ws_size,
                              hipStream_t stream)
{
  const float* x     = (const float*)d_in[0];
  const int*   ei    = (const int*)d_in[1];
  const float* W     = (const float*)d_in[2];
  const float* att_s = (const float*)d_in[3];
  const float* att_d = (const float*)d_in[4];
  const float* bias  = (const float*)d_in[5];
  const float* gamma = (const float*)d_in[6];
  const float* beta  = (const float*)d_in[7];
  float* out = (float*)d_out;

  int N = in_sizes[0] / IN_DIM;
  int E = in_sizes[1] / 2;
  int nbins = (N + DPB - 1) >> DBITS;

  char* ws = (char*)d_ws;
  __half* xl_t = (__half*)ws;                   ws += (size_t)N*HC*sizeof(__half);
  float* a_src = (float*)ws;                    ws += (size_t)N*HEADS*sizeof(float);
  float* a_dst = (float*)ws;                    ws += (size_t)N*HEADS*sizeof(float);
  int* csr      = (int*)ws;                     ws += (size_t)E*sizeof(int);
  unsigned* tmp = (unsigned*)ws;                ws += (size_t)E*sizeof(unsigned);
  int* bincnt   = (int*)ws;                     ws += MAXBINS*sizeof(int);
  int* binstart = (int*)ws;                     ws += (MAXBINS+1)*sizeof(int);
  int* bincur   = (int*)ws;                     ws += MAXBINS*sizeof(int);
  unsigned short* Wt = (unsigned short*)ws;     ws += (size_t)HC*IN_DIM*sizeof(unsigned short);

  int gemmBlocks = (N + 63)/64;
  int scatBlocks = (E + 256*SCAT_TPE - 1)/(256*SCAT_TPE);

  hipMemsetAsync(bincnt, 0, (size_t)nbins*sizeof(int), stream);
  k_front   <<<128 + NHIST, 256, 0, stream>>>(W, Wt, ei, bincnt, E, nbins);
  k_binscan <<<1, 1024, 0, stream>>>(bincnt, binstart, bincur, nbins, E);
  k_gemm_scat<<<gemmBlocks + scatBlocks, 256, 0, stream>>>(
      x, Wt, att_s, att_d, xl_t, a_src, a_dst, N, ei, bincur, tmp, E, nbins,
      gemmBlocks);
  k_node    <<<nbins, 256, 0, stream>>>(binstart, tmp, csr,
              (const float4*)a_src, (const float4*)a_dst, xl_t,
              bias, gamma, beta, out, N);
}